// Round 12
// baseline (160.803 us; speedup 1.0000x reference)
//
#include <hip/hip_runtime.h>
#include <hip/hip_bf16.h>

#define HID  128
#define NRAD 16
#define NT   100      // atom types (emb rows)

// LDS (dynamic, 117536 B):
//   Pl  : bf16 [NT][260] (padded rows)                 52000 B
//   W3l : bf16 [128][128], XOR-swizzled rows           32768 B
//   rb  : 8 x [16 edges][256 B] per-wave r slabs       32768 B
#define PL_BYTES   (NT * 260 * 2)          // 52000
#define W3_OFF     PL_BYTES
#define W3_BYTES   (HID * HID * 2)         // 32768
#define RB_OFF     (W3_OFF + W3_BYTES)     // 84768
#define LDS_BYTES  (RB_OFF + 8 * 4096)     // 117536

// Workspace: tab = [Pbf | W3s] (84768 B, staged to LDS as one blob) | Wr32 (8192 B)
#define WS_WR_OFF  (PL_BYTES + W3_BYTES)

typedef __attribute__((ext_vector_type(4))) float f32x4;
typedef __attribute__((ext_vector_type(8))) __bf16 bf16x8;
typedef __attribute__((ext_vector_type(4))) __bf16 bf16x4;

union F8 { bf16x8 b; int4 i4; };
union B4 { bf16x4 b4; int2 i2; };

__device__ inline unsigned short f2bfbits(float f){
  unsigned int u = __float_as_uint(f);
  u += 0x7FFFu + ((u >> 16) & 1u);
  return (unsigned short)(u >> 16);
}

__device__ inline float silu_f(float v){
  return v * __builtin_amdgcn_rcpf(1.0f + __expf(-v));
}

__device__ inline float bflo(int q){ return __uint_as_float((unsigned)q << 16); }
__device__ inline float bfhi(int q){ return __uint_as_float((unsigned)q & 0xFFFF0000u); }

// ---------------------------------------------------------------------------
// Setup (one launch):
//   blocks [0, ntypes)      : Pbf[t][0:128]=emb@W1^T+b_lin ; [128:256]=emb@W2^T
//   blocks [ntypes, +64)    : W3s bf16, XOR-swizzled (byte ^= (row&7)<<4)
//   blocks [ntypes+64, +16) : Wr32 bf16 [128][32]: cols0-15=W_rbf, col16=b_rbf
// ---------------------------------------------------------------------------
__global__ void setup_kernel(const float* __restrict__ emb,
                             const float* __restrict__ W_lin,
                             const float* __restrict__ b_lin,
                             const float* __restrict__ W_rbf,
                             const float* __restrict__ b_rbf,
                             int ntypes,
                             unsigned short* __restrict__ Pbf,
                             char* __restrict__ W3s,
                             unsigned short* __restrict__ Wr32){
  int blk = blockIdx.x;
  int n = threadIdx.x;                // 0..255
  if (blk < ntypes){
    __shared__ float er[HID];
    if (n < HID) er[n] = emb[blk * HID + n];
    __syncthreads();
    int half = n >> 7, nn = n & 127;
    const float4* w4 = (const float4*)(W_lin + (size_t)nn * (3 * HID) + half * HID);
    float s = half ? 0.0f : b_lin[nn];
    #pragma unroll 8
    for (int k4 = 0; k4 < HID / 4; ++k4){
      float4 w = w4[k4];
      s += er[k4*4+0]*w.x + er[k4*4+1]*w.y + er[k4*4+2]*w.z + er[k4*4+3]*w.w;
    }
    Pbf[blk * 260 + n] = f2bfbits(s);
    if (n < 4) Pbf[blk * 260 + 256 + n] = 0;   // deterministic pad
  } else if (blk < ntypes + 64){
    int idx = (blk - ntypes) * 256 + n;        // 0..16383
    int r = idx >> 7, k = idx & 127;
    unsigned short v = f2bfbits(W_lin[(size_t)r * (3 * HID) + 2 * HID + k]);
    int byte = ((r * HID + k) * 2) ^ ((r & 7) << 4);
    *(unsigned short*)(W3s + byte) = v;
  } else {
    int idx = (blk - ntypes - 64) * 256 + n;   // 0..4095
    int r = idx >> 5, k = idx & 31;
    float v = (k < 16) ? W_rbf[r * NRAD + k] : (k == 16 ? b_rbf[r] : 0.f);
    Wr32[idx] = f2bfbits(v);
  }
}

// ---------------------------------------------------------------------------
// Edge kernel: 512 threads (8 waves), WAVE-LOCAL streaming, NO barriers.
// Each wave owns an independent grid-stride stream of 16-edge slabs:
//   phase 1: r = silu(rbf@Wrbf^T + b) (bias via augmented k=16 column)
//            -> own 4 KB swizzled LDS slab
//   phase 2: acc = W3 * r^T, W3 A-fragments read from swizzled LDS copy
//   epilogue: out = silu(acc + P1[x[i]] + P2[x[j]]), P bf16 in LDS
// Stores stream continuously (no barrier bursts) -> write-BW-bound design.
// Per-lane 1-ahead prefetch of ei/ej/rbf; x-gathers issued after phase 1.
// ---------------------------------------------------------------------------
__global__ __launch_bounds__(512, 2) void edge_kernel(
    const float* __restrict__ rbf,
    const int*   __restrict__ ei,
    const int*   __restrict__ ej,
    const int*   __restrict__ x,
    const unsigned short* __restrict__ Wr32,  // bf16 [128][32]
    const int4*  __restrict__ tab,            // Pbf | W3s blob (84768 B)
    float* __restrict__ out,
    int E, int nslab)
{
  extern __shared__ char smem[];

  const int tid  = threadIdx.x;
  const int lane = tid & 63;
  const int wv   = tid >> 6;        // 0..7
  const int erow = lane & 15;       // edge-within-slab AND W-row index
  const int kgrp = lane >> 4;       // 0..3
  char* rbw = smem + RB_OFF + wv * 4096;     // this wave's private r slab
  const unsigned short* PlU = (const unsigned short*)smem;
  const char* W3l = smem + W3_OFF;
  const int swz = (erow & 7) << 4;

  // ---- stage Pbf + W3s into LDS (one linear blob) -------------------------
  for (int i = tid; i < (PL_BYTES + W3_BYTES) / 16; i += 512)
    ((int4*)smem)[i] = tab[i];

  // ---- loop-invariant Wrbf+bias fragments ---------------------------------
  F8 wr[8];
  #pragma unroll
  for (int t = 0; t < 8; ++t)
    wr[t].i4 = *(const int4*)(Wr32 + (t * 16 + erow) * 32 + kgrp * 8);

  const int stride = gridDim.x * 8;
  int slab = blockIdx.x * 8 + wv;

  // ---- prologue: first slab's indices + rbf -------------------------------
  int xa = 0, xb = 0;
  f32x4 f0 = {0,0,0,0}, f1 = {0,0,0,0};
  if (slab < nslab){
    long ge = (long)slab * 16 + erow; if (ge > (long)E - 1) ge = E - 1;
    xa = x[ei[ge]];
    xb = x[ej[ge]];
    if (kgrp < 2){
      const f32x4* s4 = (const f32x4*)(rbf + ge * NRAD + kgrp * 8);
      f0 = __builtin_nontemporal_load(s4);
      f1 = __builtin_nontemporal_load(s4 + 1);
    }
  }

  __syncthreads();                             // tables staged (only barrier)

  while (slab < nslab){
    const long ge   = (long)slab * 16 + erow;
    const int  next = slab + stride;

    // ---- issue next slab's ei/ej + rbf loads ------------------------------
    int nei = 0, nej = 0;
    f32x4 nf0 = {0,0,0,0}, nf1 = {0,0,0,0};
    if (next < nslab){
      long gn = (long)next * 16 + erow; if (gn > (long)E - 1) gn = E - 1;
      nei = ei[gn];
      nej = ej[gn];
      if (kgrp < 2){
        const f32x4* s4 = (const f32x4*)(rbf + gn * NRAD + kgrp * 8);
        nf0 = __builtin_nontemporal_load(s4);
        nf1 = __builtin_nontemporal_load(s4 + 1);
      }
    }

    // ---- phase 1: r for own 16 edges -> own swizzled slab -----------------
    F8 fb; fb.i4 = make_int4(0, 0, 0, 0);
    if (kgrp < 2){
      fb.b[0]=(__bf16)f0.x; fb.b[1]=(__bf16)f0.y; fb.b[2]=(__bf16)f0.z; fb.b[3]=(__bf16)f0.w;
      fb.b[4]=(__bf16)f1.x; fb.b[5]=(__bf16)f1.y; fb.b[6]=(__bf16)f1.z; fb.b[7]=(__bf16)f1.w;
    } else if (kgrp == 2){
      fb.b[0] = (__bf16)1.0f;                  // bias column (k=16)
    }
    #pragma unroll
    for (int t = 0; t < 8; ++t){
      f32x4 acc = {0.f, 0.f, 0.f, 0.f};
      acc = __builtin_amdgcn_mfma_f32_16x16x32_bf16(wr[t].b, fb.b, acc, 0, 0, 0);
      B4 pk;                                   // D: col=edge erow, row=kgrp*4+r
      pk.b4[0] = (__bf16)silu_f(acc[0]);
      pk.b4[1] = (__bf16)silu_f(acc[1]);
      pk.b4[2] = (__bf16)silu_f(acc[2]);
      pk.b4[3] = (__bf16)silu_f(acc[3]);
      int byte = (erow << 8) + t * 32 + kgrp * 8;
      byte ^= swz;
      *(int2*)(rbw + byte) = pk.i2;
    }

    // ---- next slab's x-gathers (ei/ej loads have landed under phase 1) ----
    int nxa = 0, nxb = 0;
    if (next < nslab){ nxa = x[nei]; nxb = x[nej]; }

    // wave-local RAW on rbw (DS pipe is in-order per wave; ensure compiler
    // ordering + drain before the dependent reads)
    asm volatile("s_waitcnt lgkmcnt(0)" ::: "memory");
    __builtin_amdgcn_sched_barrier(0);

    // ---- phase 2: acc = W3 * r^T (A-fragments from swizzled LDS W3) -------
    f32x4 acc2[8];
    #pragma unroll
    for (int t = 0; t < 8; ++t) acc2[t] = (f32x4){0.f, 0.f, 0.f, 0.f};

    #pragma unroll
    for (int s = 0; s < 4; ++s){
      int rbyte = ((erow << 8) + s * 64 + kgrp * 16) ^ swz;
      F8 bB; bB.i4 = *(const int4*)(rbw + rbyte);          // B: col=edge erow
      #pragma unroll
      for (int t = 0; t < 8; ++t){
        int wbyte = (((t * 16 + erow) << 8) + s * 64 + kgrp * 16) ^ swz;
        F8 aW; aW.i4 = *(const int4*)(W3l + wbyte);
        acc2[t] = __builtin_amdgcn_mfma_f32_16x16x32_bf16(aW.b, bB.b, acc2[t], 0, 0, 0);
      }
    }

    // ---- epilogue: lane owns edge ge, n = t*16 + kgrp*4 + (0..3) ----------
    const unsigned short* pa = PlU + xa * 260;
    const unsigned short* pb = PlU + xb * 260 + 128;
    #pragma unroll
    for (int t = 0; t < 8; ++t){
      const int nb = t * 16 + kgrp * 4;
      int2 q1 = *(const int2*)(pa + nb);
      int2 q2 = *(const int2*)(pb + nb);
      f32x4 o;
      o.x = silu_f(acc2[t][0] + bflo(q1.x) + bflo(q2.x));
      o.y = silu_f(acc2[t][1] + bfhi(q1.x) + bfhi(q2.x));
      o.z = silu_f(acc2[t][2] + bflo(q1.y) + bflo(q2.y));
      o.w = silu_f(acc2[t][3] + bfhi(q1.y) + bfhi(q2.y));
      if (ge < E)
        *(f32x4*)(out + ge * HID + nb) = o;
    }

    // ---- rotate pipeline ---------------------------------------------------
    f0 = nf0; f1 = nf1; xa = nxa; xb = nxb;
    slab = next;
  }
}

// ---------------------------------------------------------------------------
extern "C" void kernel_launch(void* const* d_in, const int* in_sizes, int n_in,
                              void* d_out, int out_size, void* d_ws, size_t ws_size,
                              hipStream_t stream){
  const int*   x    = (const int*)  d_in[0];
  const float* rbf  = (const float*)d_in[1];
  const int*   ei   = (const int*)  d_in[2];
  const int*   ej   = (const int*)  d_in[3];
  const float* emb  = (const float*)d_in[4];
  const float* Wrbf = (const float*)d_in[5];
  const float* brbf = (const float*)d_in[6];
  const float* Wlin = (const float*)d_in[7];
  const float* blin = (const float*)d_in[8];
  float* out = (float*)d_out;

  const int E      = in_sizes[2];
  const int ntypes = in_sizes[4] / HID;   // 100

  unsigned short* Pbf  = (unsigned short*)d_ws;
  char*           W3s  = (char*)d_ws + PL_BYTES;
  unsigned short* Wr32 = (unsigned short*)((char*)d_ws + WS_WR_OFF);

  setup_kernel<<<ntypes + 64 + 16, 256, 0, stream>>>(
      emb, Wlin, blin, Wrbf, brbf, ntypes, Pbf, W3s, Wr32);

  (void)hipFuncSetAttribute(reinterpret_cast<const void*>(&edge_kernel),
                            hipFuncAttributeMaxDynamicSharedMemorySize, LDS_BYTES);

  const int nslab = (E + 15) / 16;
  edge_kernel<<<256, 512, LDS_BYTES, stream>>>(
      rbf, ei, ej, x, Wr32, (const int4*)d_ws, out, E, nslab);
}